// Round 14
// baseline (177.480 us; speedup 1.0000x reference)
//
#include <hip/hip_runtime.h>
#include <math.h>

// (B,P,V,F,H) = (32,512,32,16,64). Round 18: v16 + REAL occupancy (A/B).
// v17 lesson: streaming-X prep (+12us) cost more than fused saved; reverted.
// Re-read of v10/v16 counters: Occ 26% = 8.3 waves/CU resident; lifetime =
// 46us x 8.3/32 = ~12us/wave = 29K cy, only ~3.6K VALU + ~550 MFMA => ~85%
// STALL. dur = work_waves x lifetime / resident_waves. The f16/32x32
// structure has NEVER run above 26%: v10/v14 were (256,3), v16 (256,2)
// (self-capped 8 waves/CU). The occupancy falsifications (v6/v7 at 70%)
// were the OLD bf16/16x16 structure. Register math says we fit more:
// v16 VGPR=60 + 64 acc-AGPRs ~ 124 unified <= 128 = (256,4) cap; LDS
// 33.8KB -> 4 blocks/CU -> 16 waves/CU (50%), 2x v16 residency, no spill.
// SINGLE variable vs v16: __launch_bounds__ (256,2) -> (256,4).
// Predict: Occ 26->45-50, fused 46->28-34 (if lifetime model right),
// WRITE_SIZE stays ~4MB (spill canary), bench ->96-103. If occ doubles
// and fused flat: occupancy falsified on this structure; floor declared.
// MFMA 32x32x16_f16: A[m=l&31][k=8*(l>>5)+j], B[k][n=l&31],
//                    D[row=(r&3)+8*(r>>2)+4*(l>>5)][col=l&31].
namespace {

typedef _Float16 f16x8 __attribute__((ext_vector_type(8)));
typedef _Float16 f16x2 __attribute__((ext_vector_type(2)));
typedef float    f32x16 __attribute__((ext_vector_type(16)));
typedef unsigned int uint;

__device__ __forceinline__ uint pkrtz(float a, float b) {
    return __builtin_bit_cast(uint, __builtin_amdgcn_cvt_pkrtz(a, b));
}
__device__ __forceinline__ uint pk_add(uint a, uint b) {
    uint r; asm("v_pk_add_f16 %0, %1, %2" : "=v"(r) : "v"(a), "v"(b)); return r;
}
__device__ __forceinline__ uint pk_mul(uint a, uint b) {
    uint r; asm("v_pk_mul_f16 %0, %1, %2" : "=v"(r) : "v"(a), "v"(b)); return r;
}
__device__ __forceinline__ uint pk_max(uint a, uint b) {
    uint r; asm("v_pk_max_f16 %0, %1, %2" : "=v"(r) : "v"(a), "v"(b)); return r;
}

// ---- prep: pack W1/W2/W3 as f16 32x32x16 B-frags + per-bp u32 masks ----
// frag f: 0..1 = W1 (ki=0, nt2=f); 2..17 = W2 (ki=(f-2)>>1, nt2=(f-2)&1);
// 18..33 = W3. Lane l of frag f holds W[32*nt2 + (l&31)][16ki + 8*(l>>5)+j].
__global__ void prep_pack(const float* __restrict__ W1, const float* __restrict__ W2,
                          const float* __restrict__ W3, const int* __restrict__ M,
                          unsigned short* __restrict__ wsW, uint* __restrict__ wsM)
{
    int t = blockIdx.x * blockDim.x + threadIdx.x;
    if (t < 34 * 64) {
        int f = t >> 6, l = t & 63, nb = l & 31, kg = l >> 5;
        const float* src; int K, ki, nt2;
        if (f < 2)       { src = W1; K = 16;  ki = 0;           nt2 = f; }
        else if (f < 18) { int g = f - 2;  src = W2; K = 128; ki = g >> 1; nt2 = g & 1; }
        else             { int g = f - 18; src = W3; K = 128; ki = g >> 1; nt2 = g & 1; }
        const float* s = src + (size_t)(32 * nt2 + nb) * K + 16 * ki + 8 * kg;
        uint4 q;
        q.x = pkrtz(s[0], s[1]); q.y = pkrtz(s[2], s[3]);
        q.z = pkrtz(s[4], s[5]); q.w = pkrtz(s[6], s[7]);
        *(uint4*)(wsW + (size_t)f * 512 + l * 8) = q;
    } else if (t < 34 * 64 + 16384) {
        int bp = t - 34 * 64;
        const int4* mp = (const int4*)(M + bp * 32);
        uint bits = 0;
        #pragma unroll
        for (int i = 0; i < 8; ++i) {
            int4 v = mp[i];
            bits |= ((v.x ? 1u : 0u) | (v.y ? 2u : 0u) |
                     (v.z ? 4u : 0u) | (v.w ? 8u : 0u)) << (4 * i);
        }
        wsM[bp] = bits;
    }
}

__global__ __launch_bounds__(256, 4) void fused_mlp_v18(
    const float* __restrict__ X, const uint* __restrict__ MPK,
    const unsigned short* __restrict__ WF,
    const float* __restrict__ B1, const float* __restrict__ B2,
    const float* __restrict__ B3, float* __restrict__ OUT)
{
    __shared__ __align__(16) unsigned char sXb[4][2][4096];  // 32768 B
    __shared__ __align__(16) _Float16 sP[4][2][64];          //  1024 B

    const int t = threadIdx.x, w = t >> 6, l = t & 63;
    const int hb = l >> 5, mtl = (l >> 4) & 1, l3 = (l >> 3) & 1;
    const size_t bp0 = (size_t)blockIdx.x * 8 + w * 2;

    unsigned char* sb[2] = { &sXb[w][0][0], &sXb[w][1][0] };
    _Float16*     pl[2] = { &sP[w][0][0],  &sP[w][1][0]  };

    // v11/v16 extended swizzle (HW-validated): write base, rows m..m+3.
    uint wb0 = (uint)((l & 7) * 32 + mtl * 256 + l3 * 1024 + hb * 8);
    wb0 ^= (uint)((mtl << 5) ^ (l3 << 4));
    const uint wb1 = (wb0 + 512u) ^ 64u;
    // read bases: parity pair (conflict-free reads).
    uint rbA = (uint)(mtl * 2048 + hb * 1024 + ((l & 15) >> 1) * 4);
    rbA ^= (uint)((hb << 4) ^ (mtl << 5));
    const uint rbB = rbA ^ 32u;
    const uint sel = (l & 1) ? 0x07060302u : 0x05040100u;  // own f16 half
    const uint SL2 = pkrtz(0.01f, 0.01f);

    const unsigned short* WFb = WF + l * 8;   // lane base into packed frags

    // ---- prefetch L2-layer W-frags (compiler may sink; harmless) ----
    uint4 wreg[16];
    #pragma unroll
    for (int f = 0; f < 16; ++f)
        wreg[f] = *(const uint4*)(WFb + (size_t)(2 + f) * 512);

    // ---- masks: packed -inf addends for pool (pairs of rows m,m+1) ----
    bool anyv[2]; uint adm[2][4][2];
    #pragma unroll
    for (int u = 0; u < 2; ++u) {
        uint mk = MPK[bp0 + u];
        anyv[u] = (mk != 0u);
        #pragma unroll
        for (int g = 0; g < 4; ++g) {   // rows 8g+4hb .. +3
            uint nib = (mk >> (8 * g + 4 * hb)) & 15u;
            adm[u][g][0] = (nib & 1u ? 0u : 0xFC00u) | (nib & 2u ? 0u : 0xFC000000u);
            adm[u][g][1] = (nib & 4u ? 0u : 0xFC00u) | (nib & 8u ? 0u : 0xFC000000u);
        }
    }

    // ---- X -> layer-1 A-frags (f16, rtz) ----
    f16x8 a1f[2];
    #pragma unroll
    for (int u = 0; u < 2; ++u) {
        const float4* xp = (const float4*)(X + ((bp0 + u) * 32 + (l & 31)) * 16 + 8 * hb);
        float4 x0 = xp[0], x1 = xp[1];
        uint4 q;
        q.x = pkrtz(x0.x, x0.y); q.y = pkrtz(x0.z, x0.w);
        q.z = pkrtz(x1.x, x1.y); q.w = pkrtz(x1.z, x1.w);
        a1f[u] = __builtin_bit_cast(f16x8, q);
    }

    // persistent zero C-input
    f32x16 zc;
    #pragma unroll
    for (int i = 0; i < 16; ++i) zc[i] = 0.f;

    f32x16 acc[2][2];   // [u][nt2]

    // ---- layer 1 (K=16, one 32x32x16 step) ----
    {
        f16x8 wf0 = *(const f16x8*)(WFb);
        f16x8 wf1 = *(const f16x8*)(WFb + 512);
        #pragma unroll
        for (int u = 0; u < 2; ++u) {
            acc[u][0] = __builtin_amdgcn_mfma_f32_32x32x16_f16(a1f[u], wf0, zc, 0, 0, 0);
            acc[u][1] = __builtin_amdgcn_mfma_f32_32x32x16_f16(a1f[u], wf1, zc, 0, 0, 0);
        }
    }

    // ---- epilogue: +bias, lrelu, (store h to swizzled LDS), masked pool ----
    auto epi = [&](int u, const float* __restrict__ Bp, bool dostore) {
        unsigned char* sbu = sb[u];
        _Float16* plu = pl[u];
        #pragma unroll
        for (int nt2 = 0; nt2 < 2; ++nt2) {
            float bsc = Bp[32 * nt2 + (l & 31)];
            uint bpk = pkrtz(bsc, bsc);
            uint base = nt2 ? wb1 : wb0;
            uint pp = 0xFC00FC00u;   // (-inf, -inf)
            #pragma unroll
            for (int g = 0; g < 4; ++g) {   // rows m = 8g+4hb .. +3
                uint d01 = pkrtz(acc[u][nt2][4 * g + 0], acc[u][nt2][4 * g + 1]);
                uint d23 = pkrtz(acc[u][nt2][4 * g + 2], acc[u][nt2][4 * g + 3]);
                d01 = pk_add(d01, bpk);  d23 = pk_add(d23, bpk);
                d01 = pk_max(d01, pk_mul(d01, SL2));      // packed lrelu
                d23 = pk_max(d23, pk_mul(d23, SL2));
                if (dostore) {
                    uint wba = (base ^ (uint)(((g & 1) << 4) ^ ((g >> 1) << 5)))
                               + (uint)((g >> 1) * 2048);
                    uint2 st; st.x = d01; st.y = d23;
                    *(uint2*)(sbu + wba) = st;
                }
                pp = pk_max(pp, pk_add(d01, adm[u][g][0]));
                pp = pk_max(pp, pk_add(d23, adm[u][g][1]));
            }
            f16x2 ph = __builtin_bit_cast(f16x2, pp);
            float pv = fmaxf((float)ph[0], (float)ph[1]);
            pv = fmaxf(pv, __shfl_xor(pv, 32));   // merge other hb half
            pv = anyv[u] ? pv : 0.f;
            if (dostore) {
                if (l < 32) plu[32 * nt2 + (l & 31)] = (_Float16)pv;
            } else {
                if (l < 32) OUT[(bp0 + u) * 64 + 32 * nt2 + (l & 31)] = pv;
            }
        }
    };

    // ---- K=128 layer from wreg; optional refill with next layer's frags ----
    auto layerK = [&](bool refill, int fb_next) {
        #pragma unroll
        for (int ki = 0; ki < 8; ++ki) {
            f16x8 wf0 = __builtin_bit_cast(f16x8, wreg[2 * ki]);
            f16x8 wf1 = __builtin_bit_cast(f16x8, wreg[2 * ki + 1]);
            #pragma unroll
            for (int u = 0; u < 2; ++u) {
                f16x8 a;
                if (ki < 4) {
                    const unsigned char* pA = sb[u] + rbA + 256 * ki;
                    const unsigned char* pB = sb[u] + rbB + 256 * ki;
                    uint F[8];
                    #pragma unroll
                    for (int j = 0; j < 8; ++j) {
                        const int e = j ^ ki;
                        F[j] = *(const uint*)(((e & 1) ? pB : pA) + 32 * (e & ~1));
                    }
                    uint4 q;
                    q.x = __builtin_amdgcn_perm(F[1], F[0], sel);
                    q.y = __builtin_amdgcn_perm(F[3], F[2], sel);
                    q.z = __builtin_amdgcn_perm(F[5], F[4], sel);
                    q.w = __builtin_amdgcn_perm(F[7], F[6], sel);
                    a = __builtin_bit_cast(f16x8, q);
                } else {
                    a = *(const f16x8*)(pl[u] + 16 * (ki - 4) + 8 * hb);  // bcast
                }
                acc[u][0] = __builtin_amdgcn_mfma_f32_32x32x16_f16(
                    a, wf0, ki == 0 ? zc : acc[u][0], 0, 0, 0);
                acc[u][1] = __builtin_amdgcn_mfma_f32_32x32x16_f16(
                    a, wf1, ki == 0 ? zc : acc[u][1], 0, 0, 0);
            }
            if (refill) {
                wreg[2 * ki]     = *(const uint4*)(WFb + (size_t)(fb_next + 2 * ki) * 512);
                wreg[2 * ki + 1] = *(const uint4*)(WFb + (size_t)(fb_next + 2 * ki + 1) * 512);
            }
        }
    };

    epi(0, B1, true);  epi(1, B1, true);    // L2 W-loads land here
    layerK(true, 18);                        // consume L2, issue L3 loads
    epi(0, B2, true);  epi(1, B2, true);    // L3 W-loads land here
    layerK(false, 0);
    epi(0, B3, false); epi(1, B3, false);   // layer-3 pool == final output
}
} // namespace

extern "C" void kernel_launch(void* const* d_in, const int* in_sizes, int n_in,
                              void* d_out, int out_size, void* d_ws, size_t ws_size,
                              hipStream_t stream) {
    (void)in_sizes; (void)n_in; (void)ws_size; (void)out_size;
    const float* X  = (const float*)d_in[0];
    const int*   M  = (const int*)d_in[1];
    const float* W1 = (const float*)d_in[2];
    const float* B1 = (const float*)d_in[3];
    const float* W2 = (const float*)d_in[4];
    const float* B2 = (const float*)d_in[5];
    const float* W3 = (const float*)d_in[6];
    const float* B3 = (const float*)d_in[7];
    float* OUT = (float*)d_out;

    unsigned short* WF  = (unsigned short*)d_ws;              // 34816 B
    uint*           MPK = (uint*)((char*)d_ws + 34816);       // 65536 B

    prep_pack<<<(34 * 64 + 16384 + 255) / 256, 256, 0, stream>>>(W1, W2, W3, M, WF, MPK);
    // 2048 blocks x 4 waves x 2 bp = 16384 bp; two bp per wave
    fused_mlp_v18<<<2048, 256, 0, stream>>>(X, MPK, WF, B1, B2, B3, OUT);
}

// Round 15
// 115.286 us; speedup vs baseline: 1.5395x; 1.5395x over previous
//
#include <hip/hip_runtime.h>
#include <math.h>

// (B,P,V,F,H) = (32,512,32,16,64). Round 19: CLEAN occupancy A/B (1 bp/wave).
// v18's (256,4) test was invalidated by its own spill canary (WRITE 4->132MB:
// acc 64 + wreg 64 > 128-reg cap). wreg was worth ~0 (v16 114.3 vs v10
// 114.8), so drop it AND halve per-wave state to run the occupancy
// experiment honestly: ONE bp per wave ->
//   regs: acc 32 + zc 16 + adm 8 + a1f 4 + temps ~20 ~= 80 << 128 cap;
//   LDS 16.9KB/block -> 4 blocks/CU @ (256,4) = 16 waves/CU (50%), 2x v10;
//   grid 4096 x 4 waves = 16384 waves, one bp each; W streamed per-ki from
//   WF exactly like v10 (our best fused kernel).
// Residency model predicts: lifetime ~0.7x (half MFMA/VALU per phase, same
// stall count), work waves 2x, residency 1.9x -> fused ~0.73x ~= 32-36us.
// Gates: WRITE_SIZE ~4MB (no spill) + Occ ~45-50%. If both hold and fused
// stays ~46: occupancy is CLEANLY falsified on this structure -> declare
// floor at v16 next round.
// MFMA 32x32x16_f16: A[m=l&31][k=8*(l>>5)+j], B[k][n=l&31],
//                    D[row=(r&3)+8*(r>>2)+4*(l>>5)][col=l&31].
namespace {

typedef _Float16 f16x8 __attribute__((ext_vector_type(8)));
typedef _Float16 f16x2 __attribute__((ext_vector_type(2)));
typedef float    f32x16 __attribute__((ext_vector_type(16)));
typedef unsigned int uint;

__device__ __forceinline__ uint pkrtz(float a, float b) {
    return __builtin_bit_cast(uint, __builtin_amdgcn_cvt_pkrtz(a, b));
}
__device__ __forceinline__ uint pk_add(uint a, uint b) {
    uint r; asm("v_pk_add_f16 %0, %1, %2" : "=v"(r) : "v"(a), "v"(b)); return r;
}
__device__ __forceinline__ uint pk_mul(uint a, uint b) {
    uint r; asm("v_pk_mul_f16 %0, %1, %2" : "=v"(r) : "v"(a), "v"(b)); return r;
}
__device__ __forceinline__ uint pk_max(uint a, uint b) {
    uint r; asm("v_pk_max_f16 %0, %1, %2" : "=v"(r) : "v"(a), "v"(b)); return r;
}

// ---- prep: pack W1/W2/W3 as f16 32x32x16 B-frags + per-bp u32 masks ----
// frag f: 0..1 = W1 (ki=0, nt2=f); 2..17 = W2 (ki=(f-2)>>1, nt2=(f-2)&1);
// 18..33 = W3. Lane l of frag f holds W[32*nt2 + (l&31)][16ki + 8*(l>>5)+j].
__global__ void prep_pack(const float* __restrict__ W1, const float* __restrict__ W2,
                          const float* __restrict__ W3, const int* __restrict__ M,
                          unsigned short* __restrict__ wsW, uint* __restrict__ wsM)
{
    int t = blockIdx.x * blockDim.x + threadIdx.x;
    if (t < 34 * 64) {
        int f = t >> 6, l = t & 63, nb = l & 31, kg = l >> 5;
        const float* src; int K, ki, nt2;
        if (f < 2)       { src = W1; K = 16;  ki = 0;           nt2 = f; }
        else if (f < 18) { int g = f - 2;  src = W2; K = 128; ki = g >> 1; nt2 = g & 1; }
        else             { int g = f - 18; src = W3; K = 128; ki = g >> 1; nt2 = g & 1; }
        const float* s = src + (size_t)(32 * nt2 + nb) * K + 16 * ki + 8 * kg;
        uint4 q;
        q.x = pkrtz(s[0], s[1]); q.y = pkrtz(s[2], s[3]);
        q.z = pkrtz(s[4], s[5]); q.w = pkrtz(s[6], s[7]);
        *(uint4*)(wsW + (size_t)f * 512 + l * 8) = q;
    } else if (t < 34 * 64 + 16384) {
        int bp = t - 34 * 64;
        const int4* mp = (const int4*)(M + bp * 32);
        uint bits = 0;
        #pragma unroll
        for (int i = 0; i < 8; ++i) {
            int4 v = mp[i];
            bits |= ((v.x ? 1u : 0u) | (v.y ? 2u : 0u) |
                     (v.z ? 4u : 0u) | (v.w ? 8u : 0u)) << (4 * i);
        }
        wsM[bp] = bits;
    }
}

__global__ __launch_bounds__(256, 4) void fused_mlp_v19(
    const float* __restrict__ X, const uint* __restrict__ MPK,
    const unsigned short* __restrict__ WF,
    const float* __restrict__ B1, const float* __restrict__ B2,
    const float* __restrict__ B3, float* __restrict__ OUT)
{
    __shared__ __align__(16) unsigned char sXb[4][4096];  // 16384 B
    __shared__ __align__(16) _Float16 sP[4][64];          //   512 B

    const int t = threadIdx.x, w = t >> 6, l = t & 63;
    const int hb = l >> 5, mtl = (l >> 4) & 1, l3 = (l >> 3) & 1;
    const size_t bp = (size_t)blockIdx.x * 4 + w;   // ONE bp per wave

    unsigned char* sbu = &sXb[w][0];
    _Float16*     plu = &sP[w][0];

    // v11/v16 extended swizzle (HW-validated): write base, rows m..m+3.
    uint wb0 = (uint)((l & 7) * 32 + mtl * 256 + l3 * 1024 + hb * 8);
    wb0 ^= (uint)((mtl << 5) ^ (l3 << 4));
    const uint wb1 = (wb0 + 512u) ^ 64u;
    // read bases: parity pair (conflict-free reads).
    uint rbA = (uint)(mtl * 2048 + hb * 1024 + ((l & 15) >> 1) * 4);
    rbA ^= (uint)((hb << 4) ^ (mtl << 5));
    const uint rbB = rbA ^ 32u;
    const uint sel = (l & 1) ? 0x07060302u : 0x05040100u;  // own f16 half
    const uint SL2 = pkrtz(0.01f, 0.01f);

    const unsigned short* WFb = WF + l * 8;   // lane base into packed frags

    // ---- mask: packed -inf addends for pool (pairs of rows m,m+1) ----
    const uint mk = MPK[bp];
    const bool anyv = (mk != 0u);
    uint adm[4][2];
    #pragma unroll
    for (int g = 0; g < 4; ++g) {   // rows 8g+4hb .. +3
        uint nib = (mk >> (8 * g + 4 * hb)) & 15u;
        adm[g][0] = (nib & 1u ? 0u : 0xFC00u) | (nib & 2u ? 0u : 0xFC000000u);
        adm[g][1] = (nib & 4u ? 0u : 0xFC00u) | (nib & 8u ? 0u : 0xFC000000u);
    }

    // ---- X -> layer-1 A-frag (f16, rtz) ----
    f16x8 a1f;
    {
        const float4* xp = (const float4*)(X + (bp * 32 + (l & 31)) * 16 + 8 * hb);
        float4 x0 = xp[0], x1 = xp[1];
        uint4 q;
        q.x = pkrtz(x0.x, x0.y); q.y = pkrtz(x0.z, x0.w);
        q.z = pkrtz(x1.x, x1.y); q.w = pkrtz(x1.z, x1.w);
        a1f = __builtin_bit_cast(f16x8, q);
    }

    // persistent zero C-input
    f32x16 zc;
    #pragma unroll
    for (int i = 0; i < 16; ++i) zc[i] = 0.f;

    f32x16 acc0, acc1;   // [nt2]

    // ---- layer 1 (K=16, one 32x32x16 step) ----
    {
        f16x8 wf0 = *(const f16x8*)(WFb);
        f16x8 wf1 = *(const f16x8*)(WFb + 512);
        acc0 = __builtin_amdgcn_mfma_f32_32x32x16_f16(a1f, wf0, zc, 0, 0, 0);
        acc1 = __builtin_amdgcn_mfma_f32_32x32x16_f16(a1f, wf1, zc, 0, 0, 0);
    }

    // ---- epilogue: +bias, lrelu, (store h to swizzled LDS), masked pool ----
    auto epi = [&](const float* __restrict__ Bp, bool dostore) {
        #pragma unroll
        for (int nt2 = 0; nt2 < 2; ++nt2) {
            const f32x16& A = nt2 ? acc1 : acc0;
            float bsc = Bp[32 * nt2 + (l & 31)];
            uint bpk = pkrtz(bsc, bsc);
            uint base = nt2 ? wb1 : wb0;
            uint pp = 0xFC00FC00u;   // (-inf, -inf)
            #pragma unroll
            for (int g = 0; g < 4; ++g) {   // rows m = 8g+4hb .. +3
                uint d01 = pkrtz(A[4 * g + 0], A[4 * g + 1]);
                uint d23 = pkrtz(A[4 * g + 2], A[4 * g + 3]);
                d01 = pk_add(d01, bpk);  d23 = pk_add(d23, bpk);
                d01 = pk_max(d01, pk_mul(d01, SL2));      // packed lrelu
                d23 = pk_max(d23, pk_mul(d23, SL2));
                if (dostore) {
                    uint wba = (base ^ (uint)(((g & 1) << 4) ^ ((g >> 1) << 5)))
                               + (uint)((g >> 1) * 2048);
                    uint2 st; st.x = d01; st.y = d23;
                    *(uint2*)(sbu + wba) = st;
                }
                pp = pk_max(pp, pk_add(d01, adm[g][0]));
                pp = pk_max(pp, pk_add(d23, adm[g][1]));
            }
            f16x2 ph = __builtin_bit_cast(f16x2, pp);
            float pv = fmaxf((float)ph[0], (float)ph[1]);
            pv = fmaxf(pv, __shfl_xor(pv, 32));   // merge other hb half
            pv = anyv ? pv : 0.f;
            if (dostore) {
                if (l < 32) plu[32 * nt2 + (l & 31)] = (_Float16)pv;
            } else {
                if (l < 32) OUT[bp * 64 + 32 * nt2 + (l & 31)] = pv;
            }
        }
    };

    // ---- K=128 layer: W per-ki from WF (v10 style); ki 0..3 from swizzled
    //      h-LDS, ki 4..7 from pool broadcast ----
    auto layerK = [&](int fb) {
        #pragma unroll
        for (int ki = 0; ki < 8; ++ki) {
            const _Float16* wp = (const _Float16*)WF + (size_t)(fb + 2 * ki) * 512 + l * 8;
            f16x8 wf0 = *(const f16x8*)wp;
            f16x8 wf1 = *(const f16x8*)(wp + 512);
            f16x8 a;
            if (ki < 4) {
                const unsigned char* pA = sbu + rbA + 256 * ki;
                const unsigned char* pB = sbu + rbB + 256 * ki;
                uint F[8];
                #pragma unroll
                for (int j = 0; j < 8; ++j) {
                    const int e = j ^ ki;
                    F[j] = *(const uint*)(((e & 1) ? pB : pA) + 32 * (e & ~1));
                }
                uint4 q;
                q.x = __builtin_amdgcn_perm(F[1], F[0], sel);
                q.y = __builtin_amdgcn_perm(F[3], F[2], sel);
                q.z = __builtin_amdgcn_perm(F[5], F[4], sel);
                q.w = __builtin_amdgcn_perm(F[7], F[6], sel);
                a = __builtin_bit_cast(f16x8, q);
            } else {
                a = *(const f16x8*)(plu + 16 * (ki - 4) + 8 * hb);  // bcast
            }
            acc0 = __builtin_amdgcn_mfma_f32_32x32x16_f16(
                a, wf0, ki == 0 ? zc : acc0, 0, 0, 0);
            acc1 = __builtin_amdgcn_mfma_f32_32x32x16_f16(
                a, wf1, ki == 0 ? zc : acc1, 0, 0, 0);
        }
    };

    epi(B1, true);
    layerK(2);
    epi(B2, true);
    layerK(18);
    epi(B3, false);   // layer-3 pool == final output
}
} // namespace

extern "C" void kernel_launch(void* const* d_in, const int* in_sizes, int n_in,
                              void* d_out, int out_size, void* d_ws, size_t ws_size,
                              hipStream_t stream) {
    (void)in_sizes; (void)n_in; (void)ws_size; (void)out_size;
    const float* X  = (const float*)d_in[0];
    const int*   M  = (const int*)d_in[1];
    const float* W1 = (const float*)d_in[2];
    const float* B1 = (const float*)d_in[3];
    const float* W2 = (const float*)d_in[4];
    const float* B2 = (const float*)d_in[5];
    const float* W3 = (const float*)d_in[6];
    const float* B3 = (const float*)d_in[7];
    float* OUT = (float*)d_out;

    unsigned short* WF  = (unsigned short*)d_ws;              // 34816 B
    uint*           MPK = (uint*)((char*)d_ws + 34816);       // 65536 B

    prep_pack<<<(34 * 64 + 16384 + 255) / 256, 256, 0, stream>>>(W1, W2, W3, M, WF, MPK);
    // 4096 blocks x 4 waves; ONE bp per wave; 16 waves/CU target
    fused_mlp_v19<<<4096, 256, 0, stream>>>(X, MPK, WF, B1, B2, B3, OUT);
}